// Round 1
// baseline (681.253 us; speedup 1.0000x reference)
//
#include <hip/hip_runtime.h>

#define N_NODES 50000
#define N_EDGES 800000

// ---- edge-parallel scalar aggregation: agg[dst[e]] += x[src[e]] ----
__global__ void edge_agg_scalar(const float* __restrict__ x, const int* __restrict__ src,
                                const int* __restrict__ dst, float* __restrict__ agg, int nE) {
    int e = blockIdx.x * blockDim.x + threadIdx.x;
    if (e < nE) {
        atomicAdd(&agg[dst[e]], x[src[e]]);
    }
}

// ---- layer0 feature expansion: h0[i][j] = lrelu(agg0[i]*W0[j] + b0[j]) ----
__global__ void layer0_feat(const float* __restrict__ agg0, const float* __restrict__ W0,
                            const float* __restrict__ b0, float* __restrict__ h0, int n) {
    int gid = blockIdx.x * blockDim.x + threadIdx.x;
    if (gid < n * 64) {
        int i = gid >> 6, j = gid & 63;
        float v = agg0[i] * W0[j] + b0[j];
        h0[gid] = v >= 0.f ? v : 0.01f * v;
    }
}

// ---- edge-parallel 64-feature aggregation: gid = e*64 + j ----
__global__ void edge_agg64(const float* __restrict__ x, const int* __restrict__ src,
                           const int* __restrict__ dst, float* __restrict__ agg, int nE) {
    int gid = blockIdx.x * blockDim.x + threadIdx.x;
    if (gid < nE * 64) {
        int e = gid >> 6, j = gid & 63;
        int s = src[e], d = dst[e];
        atomicAdd(&agg[(size_t)d * 64 + j], x[(size_t)s * 64 + j]);
    }
}

// ---- Y[n,128] = lrelu(X[n,64] @ W[64,128] + b) ----
__global__ __launch_bounds__(128) void gemm64x128(const float* __restrict__ X,
                                                  const float* __restrict__ W,
                                                  const float* __restrict__ b,
                                                  float* __restrict__ Y, int n) {
    __shared__ float Ws[64 * 128];
    __shared__ float row[64];
    int tid = threadIdx.x;
    for (int idx = tid; idx < 64 * 128; idx += 128) Ws[idx] = W[idx];
    float bj = b[tid];
    int nodeBase = blockIdx.x * 32;
    for (int t = 0; t < 32; ++t) {
        int i = nodeBase + t;
        if (i >= n) break;            // uniform across block (depends only on blockIdx,t)
        __syncthreads();
        if (tid < 64) row[tid] = X[(size_t)i * 64 + tid];
        __syncthreads();
        float acc = bj;
#pragma unroll
        for (int k = 0; k < 64; ++k) acc += row[k] * Ws[k * 128 + tid];
        Y[(size_t)i * 128 + tid] = acc >= 0.f ? acc : 0.01f * acc;
    }
}

// ---- Y[n,64] = X[n,128] @ W[128,64]  (no bias/activation) ----
__global__ __launch_bounds__(64) void gemm128x64(const float* __restrict__ X,
                                                 const float* __restrict__ W,
                                                 float* __restrict__ Y, int n) {
    __shared__ float Ws[128 * 64];
    __shared__ float row[128];
    int tid = threadIdx.x;
    for (int idx = tid; idx < 128 * 64; idx += 64) Ws[idx] = W[idx];
    int nodeBase = blockIdx.x * 32;
    for (int t = 0; t < 32; ++t) {
        int i = nodeBase + t;
        if (i >= n) break;
        __syncthreads();
        row[tid] = X[(size_t)i * 128 + tid];
        row[tid + 64] = X[(size_t)i * 128 + tid + 64];
        __syncthreads();
        float acc = 0.f;
#pragma unroll
        for (int k = 0; k < 128; ++k) acc += row[k] * Ws[k * 64 + tid];
        Y[(size_t)i * 64 + tid] = acc;
    }
}

// ---- t3[i] = sum_j lrelu(agg2[i][j]+b2[j]) * W3[j]  (one wave per node) ----
__global__ void t3_kernel(const float* __restrict__ agg2, const float* __restrict__ b2,
                          const float* __restrict__ W3, float* __restrict__ t3, int n) {
    int gid = blockIdx.x * blockDim.x + threadIdx.x;
    int i = gid >> 6;   // node (one 64-lane wave per node)
    int j = gid & 63;   // feature == lane
    if (i >= n) return;
    float v = agg2[(size_t)i * 64 + j] + b2[j];
    v = v >= 0.f ? v : 0.01f * v;
    float term = v * W3[j];
    for (int off = 32; off > 0; off >>= 1)
        term += __shfl_down(term, off, 64);
    if (j == 0) t3[i] = term;
}

// ---- out[0] = lrelu(agg3[1] + b3[0]) ----
__global__ void final_k(const float* __restrict__ agg3, const float* __restrict__ b3,
                        float* __restrict__ out) {
    if (threadIdx.x == 0 && blockIdx.x == 0) {
        float v = agg3[1] + b3[0];
        out[0] = v >= 0.f ? v : 0.01f * v;
    }
}

extern "C" void kernel_launch(void* const* d_in, const int* in_sizes, int n_in,
                              void* d_out, int out_size, void* d_ws, size_t ws_size,
                              hipStream_t stream) {
    const float* in_feat = (const float*)d_in[0];
    const int*   src     = (const int*)d_in[1];
    const int*   dst     = (const int*)d_in[2];
    const float* W0      = (const float*)d_in[3];
    const float* b0      = (const float*)d_in[4];
    const float* W1      = (const float*)d_in[5];
    const float* b1      = (const float*)d_in[6];
    const float* W2      = (const float*)d_in[7];
    const float* b2      = (const float*)d_in[8];
    const float* W3      = (const float*)d_in[9];
    const float* b3      = (const float*)d_in[10];
    float* out = (float*)d_out;

    const int n = N_NODES, nE = N_EDGES;

    // workspace layout (floats): agg0[n] | h0[n*64] | agg1[n*64] | h1[n*128] | agg3[n]
    float* ws   = (float*)d_ws;
    float* agg0 = ws;
    float* h0   = agg0 + n;
    float* agg1 = h0 + (size_t)n * 64;
    float* h1   = agg1 + (size_t)n * 64;
    float* agg3 = h1 + (size_t)n * 128;
    float* t2   = h0;    // reuse: h0 dead after agg1 is built
    float* agg2 = agg1;  // reuse: agg1 dead after h1 is built
    float* t3   = agg0;  // reuse: agg0 dead after h0 is built

    // ---- layer 0: aggregate scalar, then expand to 64 feats ----
    hipMemsetAsync(agg0, 0, (size_t)n * sizeof(float), stream);
    edge_agg_scalar<<<(nE + 255) / 256, 256, 0, stream>>>(in_feat, src, dst, agg0, nE);
    layer0_feat<<<(n * 64 + 255) / 256, 256, 0, stream>>>(agg0, W0, b0, h0, n);

    // ---- layer 1: aggregate 64 feats, then @W1 + b1, lrelu ----
    hipMemsetAsync(agg1, 0, (size_t)n * 64 * sizeof(float), stream);
    edge_agg64<<<(nE * 64 + 255) / 256, 256, 0, stream>>>(h0, src, dst, agg1, nE);
    gemm64x128<<<(n + 31) / 32, 128, 0, stream>>>(agg1, W1, b1, h1, n);

    // ---- layer 2: @W2 first (128>64), then aggregate; bias+lrelu fused into t3 ----
    gemm128x64<<<(n + 31) / 32, 64, 0, stream>>>(h1, W2, t2, n);
    hipMemsetAsync(agg2, 0, (size_t)n * 64 * sizeof(float), stream);
    edge_agg64<<<(nE * 64 + 255) / 256, 256, 0, stream>>>(t2, src, dst, agg2, nE);

    // ---- layer 3: lrelu(agg2+b2) @ W3 per node, then scalar aggregate ----
    t3_kernel<<<(n * 64 + 255) / 256, 256, 0, stream>>>(agg2, b2, W3, t3, n);
    hipMemsetAsync(agg3, 0, (size_t)n * sizeof(float), stream);
    edge_agg_scalar<<<(nE + 255) / 256, 256, 0, stream>>>(t3, src, dst, agg3, nE);

    // ---- output ----
    final_k<<<1, 64, 0, stream>>>(agg3, b3, out);
}

// Round 2
// 172.404 us; speedup vs baseline: 3.9515x; 3.9515x over previous
//
#include <hip/hip_runtime.h>

#define N_NODES 50000
#define N_EDGES 800000
#define NPADB 50176      // padded flag array bytes

__device__ __forceinline__ float lrelu(float v) { return v >= 0.f ? v : 0.01f * v; }

// ---- frontier passes ----
__global__ void frontier1(const int* __restrict__ src, const int* __restrict__ dst,
                          unsigned char* __restrict__ f1, int nE) {
    int e = blockIdx.x * blockDim.x + threadIdx.x;
    if (e < nE && dst[e] == 1) f1[src[e]] = 1;
}

__global__ void frontier_next(const int* __restrict__ src, const int* __restrict__ dst,
                              const unsigned char* __restrict__ fin,
                              unsigned char* __restrict__ fout, int nE) {
    int e = blockIdx.x * blockDim.x + threadIdx.x;
    if (e < nE && fin[dst[e]]) fout[src[e]] = 1;
}

// ---- compact f1 and f2 into node lists ----
__global__ void compact12(const unsigned char* __restrict__ f1, const unsigned char* __restrict__ f2,
                          int* __restrict__ list1, int* __restrict__ cnt1,
                          int* __restrict__ list2, int* __restrict__ cnt2, int n) {
    int i = blockIdx.x * blockDim.x + threadIdx.x;
    if (i < n) {
        if (f1[i]) list1[atomicAdd(cnt1, 1)] = i;
        if (f2[i]) list2[atomicAdd(cnt2, 1)] = i;
    }
}

// ---- layer0 scalar aggregation, filtered to f3 destinations (~65k active edges) ----
__global__ void agg0_scan(const float* __restrict__ x, const int* __restrict__ src,
                          const int* __restrict__ dst, const unsigned char* __restrict__ f3,
                          float* __restrict__ agg0, int nE) {
    int e = blockIdx.x * blockDim.x + threadIdx.x;
    if (e < nE) {
        int d = dst[e];
        if (f3[d]) atomicAdd(&agg0[d], x[src[e]]);
    }
}

// ---- h0[i][j] = lrelu(agg0[i]*W0[j]+b0[j]) on f3 nodes only ----
__global__ void h0_k(const float* __restrict__ agg0, const unsigned char* __restrict__ f3,
                     const float* __restrict__ W0, const float* __restrict__ b0,
                     float* __restrict__ h0, int n) {
    int gid = blockIdx.x * blockDim.x + threadIdx.x;
    if (gid < n * 64) {
        int i = gid >> 6, j = gid & 63;
        if (f3[i]) h0[gid] = lrelu(agg0[i] * W0[j] + b0[j]);
    }
}

// ---- 64-feature aggregation, filtered by dst flag (~4k/256 active edges) ----
__global__ void agg64_scan(const float* __restrict__ x, const int* __restrict__ src,
                           const int* __restrict__ dst, const unsigned char* __restrict__ flt,
                           float* __restrict__ agg, int nE) {
    int e = blockIdx.x * blockDim.x + threadIdx.x;
    if (e < nE) {
        int d = dst[e];
        if (flt[d]) {
            int s = src[e];
            const float* xs = x + (size_t)s * 64;
            float* ad = agg + (size_t)d * 64;
#pragma unroll
            for (int j = 0; j < 64; ++j) atomicAdd(&ad[j], xs[j]);
        }
    }
}

// ---- fused: h1 = lrelu(agg1@W1+b1); t2 = h1@W2, over list2 nodes. t2 may alias agg1. ----
__global__ __launch_bounds__(128) void layer12_k(const float* __restrict__ agg1,
                                                 const int* __restrict__ list2,
                                                 const int* __restrict__ cnt2,
                                                 const float* __restrict__ W1,
                                                 const float* __restrict__ b1,
                                                 const float* __restrict__ W2,
                                                 float* __restrict__ t2) {
    __shared__ float W1s[64 * 128];
    __shared__ float W2s[128 * 64];
    __shared__ float rowA[64];
    __shared__ float rowH[128];
    int tid = threadIdx.x;
    for (int k = tid; k < 64 * 128; k += 128) { W1s[k] = W1[k]; W2s[k] = W2[k]; }
    int cnt = *cnt2;
    float bj = b1[tid];
    for (int idx = blockIdx.x; idx < cnt; idx += gridDim.x) {
        int i = list2[idx];
        __syncthreads();                     // W1s/W2s ready; rowA/rowH reuse safe
        if (tid < 64) rowA[tid] = agg1[(size_t)i * 64 + tid];
        __syncthreads();
        float acc = bj;
#pragma unroll
        for (int k = 0; k < 64; ++k) acc += rowA[k] * W1s[k * 128 + tid];
        rowH[tid] = lrelu(acc);
        __syncthreads();
        if (tid < 64) {
            float a2 = 0.f;
#pragma unroll
            for (int k = 0; k < 128; ++k) a2 += rowH[k] * W2s[k * 64 + tid];
            t2[(size_t)i * 64 + tid] = a2;   // safe alias: row i read above, only this block
        }
    }
}

// ---- t3[i] = sum_j lrelu(agg2[i][j]+b2[j])*W3[j], over list1 nodes ----
__global__ void t3_k(const float* __restrict__ agg2, const int* __restrict__ list1,
                     const int* __restrict__ cnt1, const float* __restrict__ b2,
                     const float* __restrict__ W3, float* __restrict__ t3) {
    int j = threadIdx.x;
    int cnt = *cnt1;
    for (int idx = blockIdx.x; idx < cnt; idx += gridDim.x) {
        int i = list1[idx];
        float v = lrelu(agg2[(size_t)i * 64 + j] + b2[j]);
        float term = v * W3[j];
        for (int off = 32; off > 0; off >>= 1) term += __shfl_down(term, off, 64);
        if (j == 0) t3[i] = term;
    }
}

// ---- agg3 at node 1 only ----
__global__ void agg3_scan(const float* __restrict__ t3, const int* __restrict__ src,
                          const int* __restrict__ dst, float* __restrict__ agg3, int nE) {
    int e = blockIdx.x * blockDim.x + threadIdx.x;
    if (e < nE && dst[e] == 1) atomicAdd(agg3, t3[src[e]]);
}

__global__ void final_k(const float* __restrict__ agg3, const float* __restrict__ b3,
                        float* __restrict__ out) {
    if (threadIdx.x == 0 && blockIdx.x == 0) out[0] = lrelu(agg3[0] + b3[0]);
}

extern "C" void kernel_launch(void* const* d_in, const int* in_sizes, int n_in,
                              void* d_out, int out_size, void* d_ws, size_t ws_size,
                              hipStream_t stream) {
    const float* in_feat = (const float*)d_in[0];
    const int*   src     = (const int*)d_in[1];
    const int*   dst     = (const int*)d_in[2];
    const float* W0      = (const float*)d_in[3];
    const float* b0      = (const float*)d_in[4];
    const float* W1      = (const float*)d_in[5];
    const float* b1      = (const float*)d_in[6];
    const float* W2      = (const float*)d_in[7];
    const float* b2      = (const float*)d_in[8];
    const float* W3      = (const float*)d_in[9];
    // d_in[10] = b3
    const float* b3      = (const float*)d_in[10];
    float* out = (float*)d_out;

    const int n = N_NODES, nE = N_EDGES;
    const int EB = (nE + 255) / 256;

    // ---- workspace layout ----
    // zeroed prefix: f1|f2|f3|agg0|agg1|agg2|agg3,cnt1,cnt2
    char* base = (char*)d_ws;
    size_t off = 0;
    unsigned char* f1 = (unsigned char*)(base + off); off += NPADB;
    unsigned char* f2 = (unsigned char*)(base + off); off += NPADB;
    unsigned char* f3 = (unsigned char*)(base + off); off += NPADB;
    float* agg0 = (float*)(base + off); off += 200192;                 // 50000 f padded
    float* agg1 = (float*)(base + off); off += (size_t)n * 64 * 4;     // 12.8 MB
    float* agg2 = (float*)(base + off); off += (size_t)n * 64 * 4;     // 12.8 MB
    float* agg3 = (float*)(base + off);
    int* cnt1 = (int*)(agg3 + 1);
    int* cnt2 = (int*)(agg3 + 2);
    off += 256;
    size_t zero_bytes = off;
    // non-zeroed:
    float* h0   = (float*)(base + off); off += (size_t)n * 64 * 4;     // 12.8 MB
    float* t3   = (float*)(base + off); off += 200192;
    int* list1  = (int*)(base + off);  off += 200192;
    int* list2  = (int*)(base + off);  off += 200192;
    float* t2   = agg1;  // overlay: row i of agg1 is consumed before t2 row i is written

    hipMemsetAsync(base, 0, zero_bytes, stream);

    // ---- frontiers: N1 = in-nbrs(1), N2 = in-nbrs(N1), N3 = in-nbrs(N2) ----
    frontier1<<<EB, 256, 0, stream>>>(src, dst, f1, nE);
    frontier_next<<<EB, 256, 0, stream>>>(src, dst, f1, f2, nE);
    frontier_next<<<EB, 256, 0, stream>>>(src, dst, f2, f3, nE);
    compact12<<<(n + 255) / 256, 256, 0, stream>>>(f1, f2, list1, cnt1, list2, cnt2, n);

    // ---- layer 0 (on N3) ----
    agg0_scan<<<EB, 256, 0, stream>>>(in_feat, src, dst, f3, agg0, nE);
    h0_k<<<(n * 64 + 255) / 256, 256, 0, stream>>>(agg0, f3, W0, b0, h0, n);

    // ---- layer 1 agg (dst in N2) + fused layer1-linear/layer2-linear ----
    agg64_scan<<<EB, 256, 0, stream>>>(h0, src, dst, f2, agg1, nE);
    layer12_k<<<64, 128, 0, stream>>>(agg1, list2, cnt2, W1, b1, W2, t2);

    // ---- layer 2 agg (dst in N1) + layer3 linear ----
    agg64_scan<<<EB, 256, 0, stream>>>(t2, src, dst, f1, agg2, nE);
    t3_k<<<32, 64, 0, stream>>>(agg2, list1, cnt1, b2, W3, t3);

    // ---- layer 3 agg at node 1 + output ----
    agg3_scan<<<EB, 256, 0, stream>>>(t3, src, dst, agg3, nE);
    final_k<<<1, 64, 0, stream>>>(agg3, b3, out);
}